// Round 1
// baseline (223.866 us; speedup 1.0000x reference)
//
#include <hip/hip_runtime.h>
#include <stdint.h>

typedef unsigned short u16;
typedef short s16x8 __attribute__((ext_vector_type(8)));
typedef float f32x4 __attribute__((ext_vector_type(4)));

#define LOG2E 1.44269504088896340736f

constexpr int Bc = 2, Sc = 4096, Ec = 768, Hc = 12;
constexpr int Mrows = Bc * Sc; // 8192

__device__ __forceinline__ u16 f2b(float x) {
  union { float f; uint32_t u; } v; v.f = x;
  return (u16)((v.u + 0x7FFFu + ((v.u >> 16) & 1u)) >> 16);
}

__device__ __forceinline__ void gld16(const u16* g, u16* l) {
  __builtin_amdgcn_global_load_lds(
      (const __attribute__((address_space(1))) void*)g,
      (__attribute__((address_space(3))) void*)l,
      16, 0, 0);
}

// ---------------- convert hs f32 -> bf16 ----------------
__global__ void k_cvt(const float* __restrict__ in, u16* __restrict__ out, int n) {
  int i = (blockIdx.x * blockDim.x + threadIdx.x) * 4;
  if (i >= n) return;
  const float4 v = *reinterpret_cast<const float4*>(in + i);
  ushort4 o;
  o.x = f2b(v.x); o.y = f2b(v.y); o.z = f2b(v.z); o.w = f2b(v.w);
  *reinterpret_cast<ushort4*>(out + i) = o;
}

// ---------------- transpose + convert: out[c][r] = bf16(in[r][c]) ----------------
__global__ void k_tcvt(const float* __restrict__ in, u16* __restrict__ out, int RR, int CC) {
  __shared__ float t[32][33];
  const int c0 = blockIdx.x * 32, r0 = blockIdx.y * 32;
  const int tx = threadIdx.x, ty = threadIdx.y;
#pragma unroll
  for (int i = 0; i < 32; i += 8)
    t[ty + i][tx] = in[(size_t)(r0 + ty + i) * CC + c0 + tx];
  __syncthreads();
#pragma unroll
  for (int i = 0; i < 32; i += 8)
    out[(size_t)(c0 + ty + i) * RR + r0 + tx] = f2b(t[tx][ty + i]);
}

// ---------------- QKV GEMM: A[8192x768] @ Bt[2304x768]^T, scatter epilogue ----------------
__global__ __launch_bounds__(256) void k_gemm_qkv(
    const u16* __restrict__ A, const u16* __restrict__ Bt,
    const float* __restrict__ bq, const float* __restrict__ bk, const float* __restrict__ bv,
    u16* __restrict__ q_ws, u16* __restrict__ k_ws, u16* __restrict__ vt_ws) {
  __shared__ __align__(16) u16 As[128 * 64];
  __shared__ __align__(16) u16 Bs[128 * 64];
  const int m0 = blockIdx.x * 128;
  const int n0 = blockIdx.y * 128;
  const int tid = threadIdx.x;
  const int lane = tid & 63, w = tid >> 6;
  const int wm = w >> 1, wn = w & 1;
  const int lr = lane & 15, lg = lane >> 4;

  f32x4 acc[4][4] = {};
  const int fl0 = lane * 8;

  for (int k0 = 0; k0 < Ec; k0 += 64) {
#pragma unroll
    for (int c = 0; c < 4; ++c) {
      const int f = (w * 4 + c) * 512;
      const int fl = f + fl0;
      const int row = fl >> 6, col = fl & 63;
      gld16(A + (size_t)(m0 + row) * Ec + k0 + col, &As[f]);
      gld16(Bt + (size_t)(n0 + row) * Ec + k0 + col, &Bs[f]);
    }
    __syncthreads();
    s16x8 af[4][2], bf[4][2];
#pragma unroll
    for (int i = 0; i < 4; ++i) {
#pragma unroll
      for (int ks = 0; ks < 2; ++ks) {
        af[i][ks] = *reinterpret_cast<const s16x8*>(&As[(wm * 64 + i * 16 + lr) * 64 + ks * 32 + lg * 8]);
        bf[i][ks] = *reinterpret_cast<const s16x8*>(&Bs[(wn * 64 + i * 16 + lr) * 64 + ks * 32 + lg * 8]);
      }
    }
#pragma unroll
    for (int mf = 0; mf < 4; ++mf)
#pragma unroll
      for (int nf = 0; nf < 4; ++nf) {
        acc[mf][nf] = __builtin_amdgcn_mfma_f32_16x16x32_bf16(af[mf][0], bf[nf][0], acc[mf][nf], 0, 0, 0);
        acc[mf][nf] = __builtin_amdgcn_mfma_f32_16x16x32_bf16(af[mf][1], bf[nf][1], acc[mf][nf], 0, 0, 0);
      }
    __syncthreads();
  }

  const int which = n0 / Ec; // 0=q 1=k 2=v, uniform per block (768 % 128 == 0)
#pragma unroll
  for (int nf = 0; nf < 4; ++nf) {
    const int ng = n0 + wn * 64 + nf * 16 + lr;
    const int nl = ng - which * Ec;
    const int hh = nl >> 6, dd = nl & 63;
    const float bias = (which == 0 ? bq[nl] : which == 1 ? bk[nl] : bv[nl]);
#pragma unroll
    for (int mf = 0; mf < 4; ++mf) {
      const int mg = m0 + wm * 64 + mf * 16 + lg * 4;
      const int bb = mg >> 12, ss = mg & (Sc - 1);
      const int bh = bb * Hc + hh;
      if (which == 2) {
        ushort4 pk;
        pk.x = f2b(acc[mf][nf][0] + bias);
        pk.y = f2b(acc[mf][nf][1] + bias);
        pk.z = f2b(acc[mf][nf][2] + bias);
        pk.w = f2b(acc[mf][nf][3] + bias);
        *reinterpret_cast<ushort4*>(&vt_ws[((size_t)bh * 64 + dd) * Sc + ss]) = pk;
      } else {
        u16* dst = (which == 0) ? q_ws : k_ws;
        const float scl = (which == 0) ? 0.125f : 1.0f;
#pragma unroll
        for (int r = 0; r < 4; ++r)
          dst[((size_t)bh * Sc + ss + r) * 64 + dd] = f2b((acc[mf][nf][r] + bias) * scl);
      }
    }
  }
}

// ---------------- output GEMM: ctx[8192x768] @ Wo^T[768x768], +bo, f32 out ----------------
__global__ __launch_bounds__(256) void k_gemm_out(
    const u16* __restrict__ A, const u16* __restrict__ Bt,
    const float* __restrict__ bo, float* __restrict__ out) {
  __shared__ __align__(16) u16 As[128 * 64];
  __shared__ __align__(16) u16 Bs[128 * 64];
  const int m0 = blockIdx.x * 128;
  const int n0 = blockIdx.y * 128;
  const int tid = threadIdx.x;
  const int lane = tid & 63, w = tid >> 6;
  const int wm = w >> 1, wn = w & 1;
  const int lr = lane & 15, lg = lane >> 4;

  f32x4 acc[4][4] = {};
  const int fl0 = lane * 8;

  for (int k0 = 0; k0 < Ec; k0 += 64) {
#pragma unroll
    for (int c = 0; c < 4; ++c) {
      const int f = (w * 4 + c) * 512;
      const int fl = f + fl0;
      const int row = fl >> 6, col = fl & 63;
      gld16(A + (size_t)(m0 + row) * Ec + k0 + col, &As[f]);
      gld16(Bt + (size_t)(n0 + row) * Ec + k0 + col, &Bs[f]);
    }
    __syncthreads();
    s16x8 af[4][2], bf[4][2];
#pragma unroll
    for (int i = 0; i < 4; ++i) {
#pragma unroll
      for (int ks = 0; ks < 2; ++ks) {
        af[i][ks] = *reinterpret_cast<const s16x8*>(&As[(wm * 64 + i * 16 + lr) * 64 + ks * 32 + lg * 8]);
        bf[i][ks] = *reinterpret_cast<const s16x8*>(&Bs[(wn * 64 + i * 16 + lr) * 64 + ks * 32 + lg * 8]);
      }
    }
#pragma unroll
    for (int mf = 0; mf < 4; ++mf)
#pragma unroll
      for (int nf = 0; nf < 4; ++nf) {
        acc[mf][nf] = __builtin_amdgcn_mfma_f32_16x16x32_bf16(af[mf][0], bf[nf][0], acc[mf][nf], 0, 0, 0);
        acc[mf][nf] = __builtin_amdgcn_mfma_f32_16x16x32_bf16(af[mf][1], bf[nf][1], acc[mf][nf], 0, 0, 0);
      }
    __syncthreads();
  }

#pragma unroll
  for (int nf = 0; nf < 4; ++nf) {
    const int ng = n0 + wn * 64 + nf * 16 + lr;
    const float bias = bo[ng];
#pragma unroll
    for (int mf = 0; mf < 4; ++mf) {
      const int mg = m0 + wm * 64 + mf * 16 + lg * 4;
#pragma unroll
      for (int r = 0; r < 4; ++r)
        out[(size_t)(mg + r) * Ec + ng] = acc[mf][nf][r] + bias;
    }
  }
}

// ---------------- local attention ----------------
// grid (64 chunks, 24 bh). 4 waves x 16 query rows. All key tiles are 64-aligned,
// so each tile is fully valid or fully invalid -> no masking, just clip range.
__global__ __launch_bounds__(256) void k_attn(
    const u16* __restrict__ q_ws, const u16* __restrict__ k_ws,
    const u16* __restrict__ vt_ws, u16* __restrict__ ctx_ws) {
  __shared__ __align__(16) u16 P[4][16 * 88]; // per-wave P tile, stride 88 (16B-aligned, ~2-way banks)
  const int chunk = blockIdx.x;
  const int bh = blockIdx.y;
  const int b = bh / Hc, h = bh % Hc;
  const int tid = threadIdx.x, lane = tid & 63, w = tid >> 6;
  const int lr = lane & 15, lg = lane >> 4;

  const u16* qb = q_ws + (size_t)bh * Sc * 64;
  const u16* kb = k_ws + (size_t)bh * Sc * 64;
  const u16* vb = vt_ws + (size_t)bh * 64 * Sc;

  const int qrow = chunk * 64 + w * 16 + lr;
  const s16x8 qf0 = *reinterpret_cast<const s16x8*>(&qb[(size_t)qrow * 64 + lg * 8]);
  const s16x8 qf1 = *reinterpret_cast<const s16x8*>(&qb[(size_t)qrow * 64 + 32 + lg * 8]);

  float mrow[4] = {-3e38f, -3e38f, -3e38f, -3e38f};
  float ssum[4] = {0.f, 0.f, 0.f, 0.f};
  f32x4 ctx[4] = {};

  const int t0 = chunk < 4 ? 4 - chunk : 0;
  const int t1 = chunk > 59 ? 68 - chunk : 9;
  u16* pw = &P[w][0];

  for (int t = t0; t < t1; ++t) {
    const int key0 = (chunk - 4 + t) * 64;
    // S = Q K^T (16 queries x 64 keys per wave)
    f32x4 sv[4];
#pragma unroll
    for (int nt = 0; nt < 4; ++nt) {
      const u16* kp = &kb[(size_t)(key0 + nt * 16 + lr) * 64 + lg * 8];
      const s16x8 kf0 = *reinterpret_cast<const s16x8*>(kp);
      const s16x8 kf1 = *reinterpret_cast<const s16x8*>(kp + 32);
      f32x4 z = {};
      z = __builtin_amdgcn_mfma_f32_16x16x32_bf16(qf0, kf0, z, 0, 0, 0);
      z = __builtin_amdgcn_mfma_f32_16x16x32_bf16(qf1, kf1, z, 0, 0, 0);
      sv[nt] = z;
    }
    // online softmax: rows=queries=(lg*4+r), cols=keys=(nt*16+lr)
    float scl[4];
#pragma unroll
    for (int r = 0; r < 4; ++r) {
      float v = fmaxf(fmaxf(sv[0][r], sv[1][r]), fmaxf(sv[2][r], sv[3][r]));
      v = fmaxf(v, __shfl_xor(v, 1));
      v = fmaxf(v, __shfl_xor(v, 2));
      v = fmaxf(v, __shfl_xor(v, 4));
      v = fmaxf(v, __shfl_xor(v, 8));
      const float mn = fmaxf(mrow[r], v);
      scl[r] = exp2f((mrow[r] - mn) * LOG2E);
      mrow[r] = mn;
    }
    float ps[4] = {0.f, 0.f, 0.f, 0.f};
#pragma unroll
    for (int nt = 0; nt < 4; ++nt) {
#pragma unroll
      for (int r = 0; r < 4; ++r) {
        const float p = exp2f((sv[nt][r] - mrow[r]) * LOG2E);
        ps[r] += p;
        pw[(lg * 4 + r) * 88 + nt * 16 + lr] = f2b(p);
      }
    }
#pragma unroll
    for (int r = 0; r < 4; ++r) ssum[r] = ssum[r] * scl[r] + ps[r];
#pragma unroll
    for (int nt = 0; nt < 4; ++nt)
#pragma unroll
      for (int r = 0; r < 4; ++r) ctx[nt][r] *= scl[r];
    __syncthreads(); // P write -> P read ordering (cheap safety)
    // PV: ctx += P @ V  (A from LDS, B from vt_ws rows = contiguous keys)
    const s16x8 pa0 = *reinterpret_cast<const s16x8*>(&pw[lr * 88 + lg * 8]);
    const s16x8 pa1 = *reinterpret_cast<const s16x8*>(&pw[lr * 88 + 32 + lg * 8]);
#pragma unroll
    for (int nt = 0; nt < 4; ++nt) {
      const u16* vp = &vb[(size_t)(nt * 16 + lr) * Sc + key0 + lg * 8];
      const s16x8 vf0 = *reinterpret_cast<const s16x8*>(vp);
      const s16x8 vf1 = *reinterpret_cast<const s16x8*>(vp + 32);
      ctx[nt] = __builtin_amdgcn_mfma_f32_16x16x32_bf16(pa0, vf0, ctx[nt], 0, 0, 0);
      ctx[nt] = __builtin_amdgcn_mfma_f32_16x16x32_bf16(pa1, vf1, ctx[nt], 0, 0, 0);
    }
    __syncthreads();
  }

#pragma unroll
  for (int r = 0; r < 4; ++r) {
    float v = ssum[r];
    v += __shfl_xor(v, 1);
    v += __shfl_xor(v, 2);
    v += __shfl_xor(v, 4);
    v += __shfl_xor(v, 8);
    ssum[r] = 1.f / v;
  }
  const int tok = chunk * 64 + w * 16 + lg * 4;
#pragma unroll
  for (int nt = 0; nt < 4; ++nt) {
    const int col = h * 64 + nt * 16 + lr;
#pragma unroll
    for (int r = 0; r < 4; ++r)
      ctx_ws[(size_t)(b * Sc + tok + r) * Ec + col] = f2b(ctx[nt][r] * ssum[r]);
  }
}

extern "C" void kernel_launch(void* const* d_in, const int* in_sizes, int n_in,
                              void* d_out, int out_size, void* d_ws, size_t ws_size,
                              hipStream_t stream) {
  const float* hs = (const float*)d_in[0];
  const float* Wq = (const float*)d_in[1];
  const float* bq = (const float*)d_in[2];
  const float* Wk = (const float*)d_in[3];
  const float* bk = (const float*)d_in[4];
  const float* Wv = (const float*)d_in[5];
  const float* bv = (const float*)d_in[6];
  const float* Wo = (const float*)d_in[7];
  const float* bo = (const float*)d_in[8];
  float* out = (float*)d_out;

  char* ws = (char*)d_ws;
  size_t o = 0;
  u16* hsb = (u16*)(ws + o);   o += (size_t)Mrows * Ec * 2;      // 12.6 MB
  u16* wqkvt = (u16*)(ws + o); o += (size_t)3 * Ec * Ec * 2;     // 3.5 MB
  u16* wot = (u16*)(ws + o);   o += (size_t)Ec * Ec * 2;         // 1.2 MB
  u16* q_ws = (u16*)(ws + o);  o += (size_t)Mrows * Ec * 2;      // [b,h,s,d]
  u16* k_ws = (u16*)(ws + o);  o += (size_t)Mrows * Ec * 2;      // [b,h,s,d]
  u16* vt_ws = (u16*)(ws + o); o += (size_t)Mrows * Ec * 2;      // [b,h,d,s]
  u16* ctx_ws = (u16*)(ws + o); o += (size_t)Mrows * Ec * 2;     // [b*s, e]

  const int nhs = Mrows * Ec;
  k_cvt<<<nhs / (256 * 4), 256, 0, stream>>>(hs, hsb, nhs);
  dim3 tb(32, 8);
  dim3 tg(Ec / 32, Ec / 32);
  k_tcvt<<<tg, tb, 0, stream>>>(Wq, wqkvt, Ec, Ec);
  k_tcvt<<<tg, tb, 0, stream>>>(Wk, wqkvt + (size_t)Ec * Ec, Ec, Ec);
  k_tcvt<<<tg, tb, 0, stream>>>(Wv, wqkvt + (size_t)2 * Ec * Ec, Ec, Ec);
  k_tcvt<<<tg, tb, 0, stream>>>(Wo, wot, Ec, Ec);

  k_gemm_qkv<<<dim3(Mrows / 128, (3 * Ec) / 128), 256, 0, stream>>>(
      hsb, wqkvt, bq, bk, bv, q_ws, k_ws, vt_ws);

  k_attn<<<dim3(64, Bc * Hc), 256, 0, stream>>>(q_ws, k_ws, vt_ws, ctx_ws);

  k_gemm_out<<<dim3(Mrows / 128, Ec / 128), 256, 0, stream>>>(ctx_ws, wot, bo, out);
}

// Round 2
// 207.503 us; speedup vs baseline: 1.0789x; 1.0789x over previous
//
#include <hip/hip_runtime.h>
#include <stdint.h>

typedef unsigned short u16;
typedef short s16x8 __attribute__((ext_vector_type(8)));
typedef float f32x4 __attribute__((ext_vector_type(4)));

#define LOG2E 1.44269504088896340736f

constexpr int Bc = 2, Sc = 4096, Ec = 768, Hc = 12;
constexpr int Mrows = Bc * Sc; // 8192

__device__ __forceinline__ u16 f2b(float x) {
  union { float f; uint32_t u; } v; v.f = x;
  return (u16)((v.u + 0x7FFFu + ((v.u >> 16) & 1u)) >> 16);
}

__device__ __forceinline__ void gld16(const u16* g, u16* l) {
  __builtin_amdgcn_global_load_lds(
      (const __attribute__((address_space(1))) void*)g,
      (__attribute__((address_space(3))) void*)l,
      16, 0, 0);
}

// ---------------- convert hs f32 -> bf16 ----------------
__global__ void k_cvt(const float* __restrict__ in, u16* __restrict__ out, int n) {
  int i = (blockIdx.x * blockDim.x + threadIdx.x) * 4;
  if (i >= n) return;
  const float4 v = *reinterpret_cast<const float4*>(in + i);
  ushort4 o;
  o.x = f2b(v.x); o.y = f2b(v.y); o.z = f2b(v.z); o.w = f2b(v.w);
  *reinterpret_cast<ushort4*>(out + i) = o;
}

// ---------------- transpose + convert: out[c][r] = bf16(in[r][c]) ----------------
__global__ void k_tcvt(const float* __restrict__ in, u16* __restrict__ out, int RR, int CC) {
  __shared__ float t[32][33];
  const int c0 = blockIdx.x * 32, r0 = blockIdx.y * 32;
  const int tx = threadIdx.x, ty = threadIdx.y;
#pragma unroll
  for (int i = 0; i < 32; i += 8)
    t[ty + i][tx] = in[(size_t)(r0 + ty + i) * CC + c0 + tx];
  __syncthreads();
#pragma unroll
  for (int i = 0; i < 32; i += 8)
    out[(size_t)(c0 + ty + i) * RR + r0 + tx] = f2b(t[tx][ty + i]);
}

// ---------------- QKV GEMM: A[8192x768] @ Bt[2304x768]^T, scatter epilogue ----------------
__global__ __launch_bounds__(256) void k_gemm_qkv(
    const u16* __restrict__ A, const u16* __restrict__ Bt,
    const float* __restrict__ bq, const float* __restrict__ bk, const float* __restrict__ bv,
    u16* __restrict__ q_ws, u16* __restrict__ k_ws, u16* __restrict__ vt_ws) {
  __shared__ __align__(16) u16 As[128 * 64];
  __shared__ __align__(16) u16 Bs[128 * 64];
  const int m0 = blockIdx.x * 128;
  const int n0 = blockIdx.y * 128;
  const int tid = threadIdx.x;
  const int lane = tid & 63, w = tid >> 6;
  const int wm = w >> 1, wn = w & 1;
  const int lr = lane & 15, lg = lane >> 4;

  f32x4 acc[4][4] = {};
  const int fl0 = lane * 8;

  for (int k0 = 0; k0 < Ec; k0 += 64) {
#pragma unroll
    for (int c = 0; c < 4; ++c) {
      const int f = (w * 4 + c) * 512;
      const int fl = f + fl0;
      const int row = fl >> 6, col = fl & 63;
      gld16(A + (size_t)(m0 + row) * Ec + k0 + col, &As[f]);
      gld16(Bt + (size_t)(n0 + row) * Ec + k0 + col, &Bs[f]);
    }
    __syncthreads();
    s16x8 af[4][2], bf[4][2];
#pragma unroll
    for (int i = 0; i < 4; ++i) {
#pragma unroll
      for (int ks = 0; ks < 2; ++ks) {
        af[i][ks] = *reinterpret_cast<const s16x8*>(&As[(wm * 64 + i * 16 + lr) * 64 + ks * 32 + lg * 8]);
        bf[i][ks] = *reinterpret_cast<const s16x8*>(&Bs[(wn * 64 + i * 16 + lr) * 64 + ks * 32 + lg * 8]);
      }
    }
#pragma unroll
    for (int mf = 0; mf < 4; ++mf)
#pragma unroll
      for (int nf = 0; nf < 4; ++nf) {
        acc[mf][nf] = __builtin_amdgcn_mfma_f32_16x16x32_bf16(af[mf][0], bf[nf][0], acc[mf][nf], 0, 0, 0);
        acc[mf][nf] = __builtin_amdgcn_mfma_f32_16x16x32_bf16(af[mf][1], bf[nf][1], acc[mf][nf], 0, 0, 0);
      }
    __syncthreads();
  }

  const int which = n0 / Ec; // 0=q 1=k 2=v, uniform per block (768 % 128 == 0)
#pragma unroll
  for (int nf = 0; nf < 4; ++nf) {
    const int ng = n0 + wn * 64 + nf * 16 + lr;
    const int nl = ng - which * Ec;
    const int hh = nl >> 6, dd = nl & 63;
    const float bias = (which == 0 ? bq[nl] : which == 1 ? bk[nl] : bv[nl]);
#pragma unroll
    for (int mf = 0; mf < 4; ++mf) {
      const int mg = m0 + wm * 64 + mf * 16 + lg * 4;
      const int bb = mg >> 12, ss = mg & (Sc - 1);
      const int bh = bb * Hc + hh;
      if (which == 2) {
        ushort4 pk;
        pk.x = f2b(acc[mf][nf][0] + bias);
        pk.y = f2b(acc[mf][nf][1] + bias);
        pk.z = f2b(acc[mf][nf][2] + bias);
        pk.w = f2b(acc[mf][nf][3] + bias);
        *reinterpret_cast<ushort4*>(&vt_ws[((size_t)bh * 64 + dd) * Sc + ss]) = pk;
      } else {
        u16* dst = (which == 0) ? q_ws : k_ws;
        const float scl = (which == 0) ? 0.125f : 1.0f;
#pragma unroll
        for (int r = 0; r < 4; ++r)
          dst[((size_t)bh * Sc + ss + r) * 64 + dd] = f2b((acc[mf][nf][r] + bias) * scl);
      }
    }
  }
}

// ---------------- output GEMM: ctx[8192x768] @ Wo^T[768x768], +bo, f32 out ----------------
__global__ __launch_bounds__(256) void k_gemm_out(
    const u16* __restrict__ A, const u16* __restrict__ Bt,
    const float* __restrict__ bo, float* __restrict__ out) {
  __shared__ __align__(16) u16 As[128 * 64];
  __shared__ __align__(16) u16 Bs[128 * 64];
  const int m0 = blockIdx.x * 128;
  const int n0 = blockIdx.y * 128;
  const int tid = threadIdx.x;
  const int lane = tid & 63, w = tid >> 6;
  const int wm = w >> 1, wn = w & 1;
  const int lr = lane & 15, lg = lane >> 4;

  f32x4 acc[4][4] = {};
  const int fl0 = lane * 8;

  for (int k0 = 0; k0 < Ec; k0 += 64) {
#pragma unroll
    for (int c = 0; c < 4; ++c) {
      const int f = (w * 4 + c) * 512;
      const int fl = f + fl0;
      const int row = fl >> 6, col = fl & 63;
      gld16(A + (size_t)(m0 + row) * Ec + k0 + col, &As[f]);
      gld16(Bt + (size_t)(n0 + row) * Ec + k0 + col, &Bs[f]);
    }
    __syncthreads();
    s16x8 af[4][2], bf[4][2];
#pragma unroll
    for (int i = 0; i < 4; ++i) {
#pragma unroll
      for (int ks = 0; ks < 2; ++ks) {
        af[i][ks] = *reinterpret_cast<const s16x8*>(&As[(wm * 64 + i * 16 + lr) * 64 + ks * 32 + lg * 8]);
        bf[i][ks] = *reinterpret_cast<const s16x8*>(&Bs[(wn * 64 + i * 16 + lr) * 64 + ks * 32 + lg * 8]);
      }
    }
#pragma unroll
    for (int mf = 0; mf < 4; ++mf)
#pragma unroll
      for (int nf = 0; nf < 4; ++nf) {
        acc[mf][nf] = __builtin_amdgcn_mfma_f32_16x16x32_bf16(af[mf][0], bf[nf][0], acc[mf][nf], 0, 0, 0);
        acc[mf][nf] = __builtin_amdgcn_mfma_f32_16x16x32_bf16(af[mf][1], bf[nf][1], acc[mf][nf], 0, 0, 0);
      }
    __syncthreads();
  }

#pragma unroll
  for (int nf = 0; nf < 4; ++nf) {
    const int ng = n0 + wn * 64 + nf * 16 + lr;
    const float bias = bo[ng];
#pragma unroll
    for (int mf = 0; mf < 4; ++mf) {
      const int mg = m0 + wm * 64 + mf * 16 + lg * 4;
#pragma unroll
      for (int r = 0; r < 4; ++r)
        out[(size_t)(mg + r) * Ec + ng] = acc[mf][nf][r] + bias;
    }
  }
}

// ---------------- local attention ----------------
// 1D grid of 1536 blocks, XCD-swizzled so each XCD owns 3 full (b,h) slices:
// K+V working set per XCD = 3 MB < 4 MB L2 -> the 9x window reuse is L2-served.
// 4 independent waves x 16 query rows; NO barriers (P is per-wave LDS, wave-
// local ordering via lgkmcnt). K fragments double-buffered in registers
// (prefetch t+1 during softmax/PV of t); V loads issued right after QK^T so
// their latency hides under the softmax shfl/exp chain.
__global__ __launch_bounds__(256) void k_attn(
    const u16* __restrict__ q_ws, const u16* __restrict__ k_ws,
    const u16* __restrict__ vt_ws, u16* __restrict__ ctx_ws) {
  __shared__ __align__(16) u16 P[4][16 * 88]; // per-wave P tile, stride 88
  const int lin = blockIdx.x;
  const int work = (lin & 7) * 192 + (lin >> 3); // bijective XCD swizzle (1536 % 8 == 0)
  const int chunk = work & 63;
  const int bh = work >> 6;
  const int b = bh / Hc, h = bh - b * Hc;
  const int tid = threadIdx.x, lane = tid & 63, w = tid >> 6;
  const int lr = lane & 15, lg = lane >> 4;

  const u16* qb = q_ws + (size_t)bh * Sc * 64;
  const u16* kb = k_ws + (size_t)bh * Sc * 64;
  const u16* vb = vt_ws + (size_t)bh * 64 * Sc;

  const int qrow = chunk * 64 + w * 16 + lr;
  const s16x8 qf0 = *reinterpret_cast<const s16x8*>(&qb[(size_t)qrow * 64 + lg * 8]);
  const s16x8 qf1 = *reinterpret_cast<const s16x8*>(&qb[(size_t)qrow * 64 + 32 + lg * 8]);

  float mrow[4] = {-3e38f, -3e38f, -3e38f, -3e38f};
  float ssum[4] = {0.f, 0.f, 0.f, 0.f};
  f32x4 ctx[4] = {};

  const int t0 = chunk < 4 ? 4 - chunk : 0;
  const int t1 = chunk > 59 ? 68 - chunk : 9;
  u16* pw = &P[w][0];

  auto loadK = [&](s16x8 (&kf)[4][2], int t) {
    const int key0 = (chunk - 4 + t) * 64;
#pragma unroll
    for (int nt = 0; nt < 4; ++nt) {
      const u16* kp = &kb[(size_t)(key0 + nt * 16 + lr) * 64 + lg * 8];
      kf[nt][0] = *reinterpret_cast<const s16x8*>(kp);
      kf[nt][1] = *reinterpret_cast<const s16x8*>(kp + 32);
    }
  };

  auto step = [&](s16x8 (&kf)[4][2], s16x8 (&kn)[4][2], int t) {
    const int key0 = (chunk - 4 + t) * 64;
    // S = Q K^T (16 queries x 64 keys per wave)
    f32x4 sv[4];
#pragma unroll
    for (int nt = 0; nt < 4; ++nt) {
      f32x4 z = {};
      z = __builtin_amdgcn_mfma_f32_16x16x32_bf16(qf0, kf[nt][0], z, 0, 0, 0);
      z = __builtin_amdgcn_mfma_f32_16x16x32_bf16(qf1, kf[nt][1], z, 0, 0, 0);
      sv[nt] = z;
    }
    // prefetch next K tile into the other register buffer (hidden under softmax+PV)
    if (t + 1 < t1) loadK(kn, t + 1);
    // issue V loads now; latency hides under the softmax chain
    s16x8 vf[4][2];
#pragma unroll
    for (int nt = 0; nt < 4; ++nt) {
      const u16* vp = &vb[(size_t)(nt * 16 + lr) * Sc + key0 + lg * 8];
      vf[nt][0] = *reinterpret_cast<const s16x8*>(vp);
      vf[nt][1] = *reinterpret_cast<const s16x8*>(vp + 32);
    }
    // online softmax: rows=queries=(lg*4+r), cols=keys=(nt*16+lr)
    float scl[4];
#pragma unroll
    for (int r = 0; r < 4; ++r) {
      float v = fmaxf(fmaxf(sv[0][r], sv[1][r]), fmaxf(sv[2][r], sv[3][r]));
      v = fmaxf(v, __shfl_xor(v, 1));
      v = fmaxf(v, __shfl_xor(v, 2));
      v = fmaxf(v, __shfl_xor(v, 4));
      v = fmaxf(v, __shfl_xor(v, 8));
      const float mn = fmaxf(mrow[r], v);
      scl[r] = exp2f((mrow[r] - mn) * LOG2E);
      mrow[r] = mn;
    }
    float ps[4] = {0.f, 0.f, 0.f, 0.f};
#pragma unroll
    for (int nt = 0; nt < 4; ++nt) {
#pragma unroll
      for (int r = 0; r < 4; ++r) {
        const float p = exp2f((sv[nt][r] - mrow[r]) * LOG2E);
        ps[r] += p;
        pw[(lg * 4 + r) * 88 + nt * 16 + lr] = f2b(p);
      }
    }
#pragma unroll
    for (int r = 0; r < 4; ++r) ssum[r] = ssum[r] * scl[r] + ps[r];
#pragma unroll
    for (int nt = 0; nt < 4; ++nt)
#pragma unroll
      for (int r = 0; r < 4; ++r) ctx[nt][r] *= scl[r];
    // wave-local P write->read ordering: DS ops are in-order per wave; the
    // waitcnt + sched_barrier pins the compiler (guide rule #18)
    asm volatile("s_waitcnt lgkmcnt(0)" ::: "memory");
    __builtin_amdgcn_sched_barrier(0);
    const s16x8 pa0 = *reinterpret_cast<const s16x8*>(&pw[lr * 88 + lg * 8]);
    const s16x8 pa1 = *reinterpret_cast<const s16x8*>(&pw[lr * 88 + 32 + lg * 8]);
#pragma unroll
    for (int nt = 0; nt < 4; ++nt) {
      ctx[nt] = __builtin_amdgcn_mfma_f32_16x16x32_bf16(pa0, vf[nt][0], ctx[nt], 0, 0, 0);
      ctx[nt] = __builtin_amdgcn_mfma_f32_16x16x32_bf16(pa1, vf[nt][1], ctx[nt], 0, 0, 0);
    }
  };

  s16x8 kfA[4][2], kfB[4][2];
  loadK(kfA, t0);
  for (int t = t0; t < t1; ++t) {
    if (((t - t0) & 1) == 0) step(kfA, kfB, t); // uniform parity branch -> static reg indexing
    else step(kfB, kfA, t);
  }

#pragma unroll
  for (int r = 0; r < 4; ++r) {
    float v = ssum[r];
    v += __shfl_xor(v, 1);
    v += __shfl_xor(v, 2);
    v += __shfl_xor(v, 4);
    v += __shfl_xor(v, 8);
    ssum[r] = 1.f / v;
  }
  const int tok = chunk * 64 + w * 16 + lg * 4;
#pragma unroll
  for (int nt = 0; nt < 4; ++nt) {
    const int col = h * 64 + nt * 16 + lr;
#pragma unroll
    for (int r = 0; r < 4; ++r)
      ctx_ws[(size_t)(b * Sc + tok + r) * Ec + col] = f2b(ctx[nt][r] * ssum[r]);
  }
}

extern "C" void kernel_launch(void* const* d_in, const int* in_sizes, int n_in,
                              void* d_out, int out_size, void* d_ws, size_t ws_size,
                              hipStream_t stream) {
  const float* hs = (const float*)d_in[0];
  const float* Wq = (const float*)d_in[1];
  const float* bq = (const float*)d_in[2];
  const float* Wk = (const float*)d_in[3];
  const float* bk = (const float*)d_in[4];
  const float* Wv = (const float*)d_in[5];
  const float* bv = (const float*)d_in[6];
  const float* Wo = (const float*)d_in[7];
  const float* bo = (const float*)d_in[8];
  float* out = (float*)d_out;

  char* ws = (char*)d_ws;
  size_t o = 0;
  u16* hsb = (u16*)(ws + o);   o += (size_t)Mrows * Ec * 2;      // 12.6 MB
  u16* wqkvt = (u16*)(ws + o); o += (size_t)3 * Ec * Ec * 2;     // 3.5 MB
  u16* wot = (u16*)(ws + o);   o += (size_t)Ec * Ec * 2;         // 1.2 MB
  u16* q_ws = (u16*)(ws + o);  o += (size_t)Mrows * Ec * 2;      // [b,h,s,d]
  u16* k_ws = (u16*)(ws + o);  o += (size_t)Mrows * Ec * 2;      // [b,h,s,d]
  u16* vt_ws = (u16*)(ws + o); o += (size_t)Mrows * Ec * 2;      // [b,h,d,s]
  u16* ctx_ws = (u16*)(ws + o); o += (size_t)Mrows * Ec * 2;     // [b*s, e]

  const int nhs = Mrows * Ec;
  k_cvt<<<nhs / (256 * 4), 256, 0, stream>>>(hs, hsb, nhs);
  dim3 tb(32, 8);
  dim3 tg(Ec / 32, Ec / 32);
  k_tcvt<<<tg, tb, 0, stream>>>(Wq, wqkvt, Ec, Ec);
  k_tcvt<<<tg, tb, 0, stream>>>(Wk, wqkvt + (size_t)Ec * Ec, Ec, Ec);
  k_tcvt<<<tg, tb, 0, stream>>>(Wv, wqkvt + (size_t)2 * Ec * Ec, Ec, Ec);
  k_tcvt<<<tg, tb, 0, stream>>>(Wo, wot, Ec, Ec);

  k_gemm_qkv<<<dim3(Mrows / 128, (3 * Ec) / 128), 256, 0, stream>>>(
      hsb, wqkvt, bq, bk, bv, q_ws, k_ws, vt_ws);

  k_attn<<<1536, 256, 0, stream>>>(q_ws, k_ws, vt_ws, ctx_ws);

  k_gemm_out<<<dim3(Mrows / 128, Ec / 128), 256, 0, stream>>>(ctx_ws, wot, bo, out);
}